// Round 1
// baseline (1029.338 us; speedup 1.0000x reference)
//
#include <hip/hip_runtime.h>
#include <math.h>

#define NN 50000
#define EN 200000
#define CC 4
#define HH 128
#define GG 64
#define LDSA 136  // padded row stride (bf16 elems): 2-way max bank conflict, 16B-aligned rows

typedef __attribute__((ext_vector_type(8))) short bs8;
typedef __attribute__((ext_vector_type(4))) float f32x4;

__device__ __forceinline__ unsigned short f2bf(float f) {
  unsigned int u = __float_as_uint(f);
  u += 0x7FFFu + ((u >> 16) & 1u);
  return (unsigned short)(u >> 16);
}
__device__ __forceinline__ float bf2f(unsigned short h) {
  return __uint_as_float(((unsigned int)h) << 16);
}
__device__ __forceinline__ float gelu_f(float x) {
  return 0.5f * x * (1.0f + erff(x * 0.7071067811865475f));
}

// ---------------- CSR build ----------------
__global__ __launch_bounds__(256) void count_kernel(const int* __restrict__ dst,
                                                    int* __restrict__ counts) {
  int e = blockIdx.x * 256 + threadIdx.x;
  if (e < EN) atomicAdd(&counts[dst[e]], 1);
}

__global__ __launch_bounds__(1024) void scan_kernel(const int* __restrict__ counts,
                                                    int* __restrict__ offsets,
                                                    int* __restrict__ cursor, int n) {
  __shared__ int wsum[16];
  __shared__ int woff[17];
  int tid = threadIdx.x;
  int lane = tid & 63, w = tid >> 6;
  int carry = 0;
  for (int base = 0; base < n; base += 1024) {
    int i = base + tid;
    int v = (i < n) ? counts[i] : 0;
    int s = v;
#pragma unroll
    for (int d = 1; d < 64; d <<= 1) {
      int t = __shfl_up(s, d);
      if (lane >= d) s += t;
    }
    if (lane == 63) wsum[w] = s;
    __syncthreads();
    if (tid == 0) {
      int run = 0;
#pragma unroll
      for (int j = 0; j < 16; ++j) { woff[j] = run; run += wsum[j]; }
      woff[16] = run;
    }
    __syncthreads();
    if (i < n) {
      int excl = carry + woff[w] + (s - v);
      offsets[i] = excl;
      cursor[i] = excl;
    }
    carry += woff[16];
    __syncthreads();
  }
  if (tid == 0) offsets[n] = carry;
}

__global__ __launch_bounds__(256) void fill_kernel(const int* __restrict__ dst,
                                                   int* __restrict__ cursor,
                                                   int* __restrict__ csr_e) {
  int e = blockIdx.x * 256 + threadIdx.x;
  if (e < EN) {
    int pos = atomicAdd(&cursor[dst[e]], 1);
    csr_e[pos] = e;
  }
}

// ---------------- weight prep: transpose + hi/lo bf16 split ----------------
__global__ __launch_bounds__(256) void prep_w_kernel(const float* __restrict__ src,
                                                     unsigned short* __restrict__ dsthi,
                                                     unsigned short* __restrict__ dstlo) {
  int idx = blockIdx.x * 256 + threadIdx.x;  // 64 blocks -> 16384
  int n = idx >> 7, k = idx & 127;
  float v = src[k * HH + n];        // src is [k][n]; dst is [n][k]
  unsigned short hi = f2bf(v);
  unsigned short lo = f2bf(v - bf2f(hi));
  dsthi[n * HH + k] = hi;
  dstlo[n * HH + k] = lo;
}

// ---------------- bond encoder ----------------
__global__ __launch_bounds__(256) void ee_kernel(const float* __restrict__ eattr,
                                                 const float* __restrict__ Wbe,
                                                 const float* __restrict__ bbe,
                                                 float* __restrict__ ee) {
  __shared__ float Ws[16 * HH];
  int tid = threadIdx.x;
#pragma unroll
  for (int i = 0; i < 8; ++i) Ws[tid + i * 256] = Wbe[tid + i * 256];
  __syncthreads();
  int e = blockIdx.x * 2 + (tid >> 7);
  int h = tid & 127;
  const float* ea = eattr + (size_t)e * 16;
  float acc = bbe[h];
#pragma unroll
  for (int d = 0; d < 16; ++d) acc += ea[d] * Ws[d * HH + h];
  ee[(size_t)e * HH + h] = acc;
}

// ---------------- message aggregation (one wave per node, all 4 centroids) --------
__global__ __launch_bounds__(256) void agg_kernel(const float* __restrict__ x,
                                                  const float* __restrict__ ee,
                                                  const float* __restrict__ emask,
                                                  const int* __restrict__ src,
                                                  const int* __restrict__ off,
                                                  const int* __restrict__ csr_e,
                                                  const float* __restrict__ epsp, int layer,
                                                  float* __restrict__ hout) {
  int wv = threadIdx.x >> 6, lane = threadIdx.x & 63;
  int v = blockIdx.x * 4 + wv;
  int h2 = lane * 2;
  float2 acc[CC];
#pragma unroll
  for (int c = 0; c < CC; ++c) { acc[c].x = 0.f; acc[c].y = 0.f; }
  int beg = off[v], end = off[v + 1];
  for (int t = beg; t < end; ++t) {
    int e = csr_e[t];
    int s = src[e];
    float2 ev = *(const float2*)(ee + (size_t)e * HH + h2);
#pragma unroll
    for (int c = 0; c < CC; ++c) {
      float em = emask[c * EN + e];
      float2 xv = *(const float2*)(x + (size_t)(c * NN + s) * HH + h2);
      acc[c].x += gelu_f(xv.x + ev.x) * em;
      acc[c].y += gelu_f(xv.y + ev.y) * em;
    }
  }
  float ep = 1.0f + epsp[layer];
#pragma unroll
  for (int c = 0; c < CC; ++c) {
    float2 xs = *(const float2*)(x + (size_t)(c * NN + v) * HH + h2);
    float2 o;
    o.x = ep * xs.x + acc[c].x;
    o.y = ep * xs.y + acc[c].y;
    *(float2*)(hout + (size_t)(c * NN + v) * HH + h2) = o;
  }
}

// ---------------- fused MLP: out = [gelu]( gelu(in@W1+b1)@W2+b2 ), split-bf16 MFMA ----
__global__ __launch_bounds__(256) void mlp_kernel(const float* __restrict__ in,
                                                  const unsigned short* __restrict__ w1hi,
                                                  const unsigned short* __restrict__ w1lo,
                                                  const float* __restrict__ b1,
                                                  const unsigned short* __restrict__ w2hi,
                                                  const unsigned short* __restrict__ w2lo,
                                                  const float* __restrict__ b2,
                                                  float* __restrict__ out, int outer_gelu) {
  __shared__ __align__(16) unsigned short Ahi[32 * LDSA];
  __shared__ __align__(16) unsigned short Alo[32 * LDSA];
  __shared__ __align__(16) unsigned short W[128 * LDSA];
  int tid = threadIdx.x;
  int row0 = blockIdx.x * 32;
  // stage A (32 rows x 128 f32 -> hi/lo bf16)
#pragma unroll
  for (int i = 0; i < 4; ++i) {
    int idx = tid + i * 256;  // 1024 float4 chunks
    int r = idx >> 5, c4 = idx & 31;
    float4 vv = *(const float4*)(in + (size_t)(row0 + r) * HH + c4 * 4);
    unsigned short h0 = f2bf(vv.x), h1 = f2bf(vv.y), h2 = f2bf(vv.z), h3 = f2bf(vv.w);
    ushort4 hv; hv.x = h0; hv.y = h1; hv.z = h2; hv.w = h3;
    ushort4 lv;
    lv.x = f2bf(vv.x - bf2f(h0)); lv.y = f2bf(vv.y - bf2f(h1));
    lv.z = f2bf(vv.z - bf2f(h2)); lv.w = f2bf(vv.w - bf2f(h3));
    *(ushort4*)(Ahi + r * LDSA + c4 * 4) = hv;
    *(ushort4*)(Alo + r * LDSA + c4 * 4) = lv;
  }
  auto loadw = [&](const unsigned short* srcw) {
#pragma unroll
    for (int i = 0; i < 8; ++i) {
      int idx = tid + i * 256;  // 2048 chunks of 8
      int r = idx >> 4, c8 = idx & 15;
      *(bs8*)(W + r * LDSA + c8 * 8) = *(const bs8*)(srcw + r * HH + c8 * 8);
    }
  };
  loadw(w1hi);

  int lane = tid & 63, wv = tid >> 6;
  int band = (wv >> 1) * 16;  // 16-row band
  int nh = wv & 1;            // column half
  int ln = lane & 15, quad = lane >> 4;

  __syncthreads();  // B1
  bs8 ahi[4], alo[4];
#pragma unroll
  for (int ks = 0; ks < 4; ++ks) {
    ahi[ks] = *(const bs8*)(Ahi + (band + ln) * LDSA + ks * 32 + quad * 8);
    alo[ks] = *(const bs8*)(Alo + (band + ln) * LDSA + ks * 32 + quad * 8);
  }
  f32x4 acc[4];
#pragma unroll
  for (int nt = 0; nt < 4; ++nt)
#pragma unroll
    for (int r = 0; r < 4; ++r) acc[nt][r] = 0.f;
  // GEMM1 pass 1: W1 hi  (a_hi*b_hi + a_lo*b_hi)
#pragma unroll
  for (int ks = 0; ks < 4; ++ks)
#pragma unroll
    for (int nt = 0; nt < 4; ++nt) {
      bs8 b = *(const bs8*)(W + (nh * 64 + nt * 16 + ln) * LDSA + ks * 32 + quad * 8);
      acc[nt] = __builtin_amdgcn_mfma_f32_16x16x32_bf16(alo[ks], b, acc[nt], 0, 0, 0);
      acc[nt] = __builtin_amdgcn_mfma_f32_16x16x32_bf16(ahi[ks], b, acc[nt], 0, 0, 0);
    }
  __syncthreads();  // B2
  loadw(w1lo);
  __syncthreads();  // B3
  // GEMM1 pass 2: W1 lo  (a_hi*b_lo)
#pragma unroll
  for (int ks = 0; ks < 4; ++ks)
#pragma unroll
    for (int nt = 0; nt < 4; ++nt) {
      bs8 b = *(const bs8*)(W + (nh * 64 + nt * 16 + ln) * LDSA + ks * 32 + quad * 8);
      acc[nt] = __builtin_amdgcn_mfma_f32_16x16x32_bf16(ahi[ks], b, acc[nt], 0, 0, 0);
    }
  __syncthreads();  // B4
  // t = gelu(acc + b1) -> write back into A (hi/lo), and load W2 hi
#pragma unroll
  for (int nt = 0; nt < 4; ++nt) {
    int col = nh * 64 + nt * 16 + ln;
    float bb = b1[col];
#pragma unroll
    for (int r = 0; r < 4; ++r) {
      float tv = gelu_f(acc[nt][r] + bb);
      unsigned short th = f2bf(tv);
      unsigned short tl = f2bf(tv - bf2f(th));
      int rr = band + quad * 4 + r;
      Ahi[rr * LDSA + col] = th;
      Alo[rr * LDSA + col] = tl;
    }
  }
  loadw(w2hi);
  __syncthreads();  // B5
#pragma unroll
  for (int ks = 0; ks < 4; ++ks) {
    ahi[ks] = *(const bs8*)(Ahi + (band + ln) * LDSA + ks * 32 + quad * 8);
    alo[ks] = *(const bs8*)(Alo + (band + ln) * LDSA + ks * 32 + quad * 8);
  }
#pragma unroll
  for (int nt = 0; nt < 4; ++nt)
#pragma unroll
    for (int r = 0; r < 4; ++r) acc[nt][r] = 0.f;
  // GEMM2 pass 1: W2 hi
#pragma unroll
  for (int ks = 0; ks < 4; ++ks)
#pragma unroll
    for (int nt = 0; nt < 4; ++nt) {
      bs8 b = *(const bs8*)(W + (nh * 64 + nt * 16 + ln) * LDSA + ks * 32 + quad * 8);
      acc[nt] = __builtin_amdgcn_mfma_f32_16x16x32_bf16(alo[ks], b, acc[nt], 0, 0, 0);
      acc[nt] = __builtin_amdgcn_mfma_f32_16x16x32_bf16(ahi[ks], b, acc[nt], 0, 0, 0);
    }
  __syncthreads();  // B6
  loadw(w2lo);
  __syncthreads();  // B7
  // GEMM2 pass 2: W2 lo
#pragma unroll
  for (int ks = 0; ks < 4; ++ks)
#pragma unroll
    for (int nt = 0; nt < 4; ++nt) {
      bs8 b = *(const bs8*)(W + (nh * 64 + nt * 16 + ln) * LDSA + ks * 32 + quad * 8);
      acc[nt] = __builtin_amdgcn_mfma_f32_16x16x32_bf16(ahi[ks], b, acc[nt], 0, 0, 0);
    }
  // epilogue
#pragma unroll
  for (int nt = 0; nt < 4; ++nt) {
    int col = nh * 64 + nt * 16 + ln;
    float bb = b2[col];
#pragma unroll
    for (int r = 0; r < 4; ++r) {
      float o = acc[nt][r] + bb;
      if (outer_gelu) o = gelu_f(o);
      out[(size_t)(row0 + band + quad * 4 + r) * HH + col] = o;
    }
  }
}

// ---------------- masked mean pool ----------------
__global__ __launch_bounds__(256) void pool_kernel(const float* __restrict__ y,
                                                   const int* __restrict__ batch,
                                                   const float* __restrict__ nmask,
                                                   float* __restrict__ outp) {
  __shared__ float sacc[256], sden[256];
  int tid = threadIdx.x;
  int f = tid & 127, half = tid >> 7;
  int g = blockIdx.x >> 2, c = blockIdx.x & 3;
  int lo = 0, hi = NN;
  while (lo < hi) { int m = (lo + hi) >> 1; if (batch[m] < g) lo = m + 1; else hi = m; }
  int start = lo;
  hi = NN;
  while (lo < hi) { int m = (lo + hi) >> 1; if (batch[m] < g + 1) lo = m + 1; else hi = m; }
  int end = lo;
  float acc = 0.f, den = 0.f;
  for (int n = start + half; n < end; n += 2) {
    float m = nmask[c * NN + n];
    acc += y[(size_t)(c * NN + n) * HH + f] * m;
    den += m;
  }
  sacc[tid] = acc; sden[tid] = den;
  __syncthreads();
  if (half == 0) {
    float a = sacc[tid] + sacc[tid + 128];
    float d = sden[tid] + sden[tid + 128];
    outp[(size_t)(g * CC + c) * HH + f] = a / (d + 1e-7f);
  }
}

extern "C" void kernel_launch(void* const* d_in, const int* in_sizes, int n_in,
                              void* d_out, int out_size, void* d_ws, size_t ws_size,
                              hipStream_t stream) {
  const float* x_in  = (const float*)d_in[0];
  const int*   batch = (const int*)d_in[1];
  const int*   eidx  = (const int*)d_in[2];
  const float* eattr = (const float*)d_in[3];
  const float* nmask = (const float*)d_in[4];
  const float* emask = (const float*)d_in[5];
  const float* Wbe   = (const float*)d_in[6];
  const float* bbe   = (const float*)d_in[7];
  const float* epsp  = (const float*)d_in[8];
  const float* W1    = (const float*)d_in[9];
  const float* b1    = (const float*)d_in[10];
  const float* W2    = (const float*)d_in[11];
  const float* b2    = (const float*)d_in[12];
  const float* Wm1   = (const float*)d_in[13];
  const float* bm1   = (const float*)d_in[14];
  const float* Wm2   = (const float*)d_in[15];
  const float* bm2   = (const float*)d_in[16];
  float* outp = (float*)d_out;

  const int* srcp = eidx;
  const int* dstp = eidx + EN;

  // workspace carve (~309 MB)
  char* ws = (char*)d_ws;
  float* ee   = (float*)(ws);                  // 102,400,000
  float* hbuf = (float*)(ws + 102400000);      // 102,400,000
  float* xbuf = (float*)(ws + 204800000);      // 102,400,000
  int* counts  = (int*)(ws + 307200000);       // N
  int* offsets = counts + NN;                  // N+1
  int* cursor  = offsets + NN + 1;             // N
  int* csr_e   = cursor + NN;                  // E
  unsigned short* wts = (unsigned short*)(ws + 307200000 + 1400016);  // 12*16384 bf16, 16B-aligned
  unsigned short* w1hi0 = wts + 0 * 16384;
  unsigned short* w1lo0 = wts + 1 * 16384;
  unsigned short* w2hi0 = wts + 2 * 16384;
  unsigned short* w2lo0 = wts + 3 * 16384;
  unsigned short* w1hi1 = wts + 4 * 16384;
  unsigned short* w1lo1 = wts + 5 * 16384;
  unsigned short* w2hi1 = wts + 6 * 16384;
  unsigned short* w2lo1 = wts + 7 * 16384;
  unsigned short* wm1hi = wts + 8 * 16384;
  unsigned short* wm1lo = wts + 9 * 16384;
  unsigned short* wm2hi = wts + 10 * 16384;
  unsigned short* wm2lo = wts + 11 * 16384;

  // CSR build (dst-sorted, reused for both layers and all centroids)
  hipMemsetAsync(counts, 0, NN * sizeof(int), stream);
  count_kernel<<<(EN + 255) / 256, 256, 0, stream>>>(dstp, counts);
  scan_kernel<<<1, 1024, 0, stream>>>(counts, offsets, cursor, NN);
  fill_kernel<<<(EN + 255) / 256, 256, 0, stream>>>(dstp, cursor, csr_e);

  // weight prep
  prep_w_kernel<<<64, 256, 0, stream>>>(W1, w1hi0, w1lo0);
  prep_w_kernel<<<64, 256, 0, stream>>>(W1 + 16384, w1hi1, w1lo1);
  prep_w_kernel<<<64, 256, 0, stream>>>(W2, w2hi0, w2lo0);
  prep_w_kernel<<<64, 256, 0, stream>>>(W2 + 16384, w2hi1, w2lo1);
  prep_w_kernel<<<64, 256, 0, stream>>>(Wm1, wm1hi, wm1lo);
  prep_w_kernel<<<64, 256, 0, stream>>>(Wm2, wm2hi, wm2lo);

  // bond encoder (shared across layers)
  ee_kernel<<<EN / 2, 256, 0, stream>>>(eattr, Wbe, bbe, ee);

  // layer 0
  agg_kernel<<<NN / 4, 256, 0, stream>>>(x_in, ee, emask, srcp, offsets, csr_e, epsp, 0, hbuf);
  mlp_kernel<<<(CC * NN) / 32, 256, 0, stream>>>(hbuf, w1hi0, w1lo0, b1, w2hi0, w2lo0, b2, xbuf, 1);
  // layer 1
  agg_kernel<<<NN / 4, 256, 0, stream>>>(xbuf, ee, emask, srcp, offsets, csr_e, epsp, 1, hbuf);
  mlp_kernel<<<(CC * NN) / 32, 256, 0, stream>>>(hbuf, w1hi1, w1lo1, b1 + 128, w2hi1, w2lo1, b2 + 128, xbuf, 1);
  // final node MLP (no outer gelu)
  mlp_kernel<<<(CC * NN) / 32, 256, 0, stream>>>(xbuf, wm1hi, wm1lo, bm1, wm2hi, wm2lo, bm2, hbuf, 0);
  // masked mean pool -> (g,c) ordering
  pool_kernel<<<GG * CC, 256, 0, stream>>>(hbuf, batch, nmask, outp);
}